// Round 19
// baseline (116.184 us; speedup 1.0000x reference)
//
#include <hip/hip_runtime.h>
#include <stdint.h>

typedef __attribute__((ext_vector_type(4))) float f32x4;
typedef __attribute__((ext_vector_type(8))) __bf16 bf16v8;
typedef __attribute__((ext_vector_type(8))) unsigned short u16x8;
typedef __attribute__((ext_vector_type(4))) unsigned short u16x4;
typedef unsigned short u16;

#define AS1 __attribute__((address_space(1)))
#define AS3 __attribute__((address_space(3)))

__device__ __forceinline__ u16 f2b(float f) {
  union { __bf16 h; u16 u; } c; c.h = (__bf16)f; return c.u;
}

__device__ __forceinline__ f32x4 mfma16(bf16v8 a, bf16v8 b, f32x4 c) {
  return __builtin_amdgcn_mfma_f32_16x16x32_bf16(a, b, c, 0, 0, 0);
}

__device__ __forceinline__ void gl_lds16(const void* g, void* l) {
  __builtin_amdgcn_global_load_lds((AS1 void*)g, (AS3 void*)l, 16, 0, 0);
}

// ------------------------------------------------- pack x (+ bias tail) ----
__global__ __launch_bounds__(256) void pack_x_kernel(
    const float* __restrict__ x, u16* __restrict__ xb, int n8,
    const float* __restrict__ bq, const float* __restrict__ bk,
    const float* __restrict__ bv, float* __restrict__ bc, float sq) {
  int i = blockIdx.x * 256 + threadIdx.x;
  if (i < n8) {
    const f32x4* p = (const f32x4*)(x + (size_t)i * 8);
    f32x4 a = p[0], b = p[1];
    u16x8 o;
    o[0] = f2b(a[0]); o[1] = f2b(a[1]); o[2] = f2b(a[2]); o[3] = f2b(a[3]);
    o[4] = f2b(b[0]); o[5] = f2b(b[1]); o[6] = f2b(b[2]); o[7] = f2b(b[3]);
    *(u16x8*)(xb + (size_t)i * 8) = o;
  } else {
    int j = i - n8;
    if (j < 768) bc[j] = bq[j] * sq;
    else if (j < 1536) bc[j] = bk[j - 768];
    else if (j < 2304) bc[j] = bv[j - 1536];
  }
}

// --------------------------------------------------- pack all weights ------
__global__ __launch_bounds__(256) void pack_w_all(
    const float* __restrict__ wq, const float* __restrict__ wk,
    const float* __restrict__ wv, const float* __restrict__ wo,
    u16* __restrict__ btqkv, u16* __restrict__ wot, float sq) {
  __shared__ float t[64][65];
  const int z = blockIdx.z;
  const int which = z / 12, n = z % 12;
  const int c = threadIdx.x & 63, w = threadIdx.x >> 6;

  const float* in; u16* out; int in_rs; float scale;
  int a0, b0;
  if (which == 0)      { in = wq; out = btqkv;           in_rs = 64;  scale = sq;  }
  else if (which == 1) { in = wk; out = btqkv + 589824;  in_rs = 64;  scale = 1.f; }
  else if (which == 2) { in = wv; out = btqkv + 1179648; in_rs = 64;  scale = 1.f; }
  else                 { in = wo; out = wot;             in_rs = 768; scale = 1.f; }
  if (which < 3) { a0 = blockIdx.x * 64; b0 = 0; }
  else           { a0 = 0; b0 = blockIdx.x * 64; }

  const float* ip = in + (size_t)n * 49152;
#pragma unroll
  for (int i = 0; i < 16; ++i) {
    int r = i * 4 + w;
    t[r][c] = ip[(size_t)(a0 + r) * in_rs + (b0 + c)];
  }
  __syncthreads();
  u16* op = out + (size_t)n * ((which < 3) ? 49152 : 64);
#pragma unroll
  for (int i = 0; i < 16; ++i) {
    int r = i * 4 + w;
    op[(size_t)(b0 + r) * 768 + (a0 + c)] = f2b(t[c][r] * scale);
  }
}

// ------------------------------------------------- fused QKV projection ----
// R12 tile (128x192) and the SAME sound one-__syncthreads-per-K-step sync,
// but 512 threads / 8 waves per block -> 24 waves/CU (6/SIMD) to hide the
// stage/L2 latency that left the 256-thread version at 4333 cyc/K-step
// (ledger: LDS 1440 + MFMA 1400 + L2 1070, none saturated -> TLP-starved).
// Wave (wr=wid>>2, wc=wid&3) owns 64x48; acc[4][3] = 48 VGPR (fits the
// 85-VGPR cap of launch_bounds(512,6)).  Staging: linear tid*16 dests.
__global__ __launch_bounds__(512, 6) void gemm_qkv(
    const u16* __restrict__ A, const u16* __restrict__ Bt,
    u16* __restrict__ QKb, u16* __restrict__ Vtb,
    const float* __restrict__ bias) {
  __shared__ u16 lA[2][128 * 32];
  __shared__ u16 lB[2][192 * 32];

  const int tid = threadIdx.x;
  const int lane = tid & 63, wid = tid >> 6;
  const int g = lane >> 4, l16 = lane & 15;
  const int wr = wid >> 2, wc = wid & 3;
  const int m0 = blockIdx.x * 128, n0 = blockIdx.y * 192;

  const int srow = tid >> 2;          // 0..127
  const int scol = (tid & 3) * 16;    // byte offset in 64B row

  f32x4 acc[4][3];
#pragma unroll
  for (int i = 0; i < 4; ++i)
#pragma unroll
    for (int j = 0; j < 3; ++j) acc[i][j] = (f32x4)0.f;

  const char* Ab = (const char*)(A + (size_t)m0 * 768);
  const char* Bb = (const char*)(Bt + (size_t)n0 * 768);
  char* lAb = (char*)&lA[0][0];
  char* lBb = (char*)&lB[0][0];

#define QSTAGE(buf, kt)                                                         \
  do {                                                                          \
    int kb = (kt) * 64;                                                         \
    gl_lds16(Ab + (size_t)srow * 1536 + kb + scol,                              \
             lAb + (buf) * 8192 + tid * 16);                                    \
    gl_lds16(Bb + (size_t)srow * 1536 + kb + scol,                              \
             lBb + (buf) * 12288 + tid * 16);                                   \
    if (srow < 64)                                                              \
      gl_lds16(Bb + (size_t)(128 + srow) * 1536 + kb + scol,                    \
               lBb + (buf) * 12288 + 8192 + tid * 16);                          \
  } while (0)

  QSTAGE(0, 0);
  __syncthreads();

  for (int kt = 0; kt < 24; ++kt) {
    const int cur = kt & 1;
    if (kt + 1 < 24) QSTAGE(cur ^ 1, kt + 1);
    bf16v8 af[4], bfv[3];
#pragma unroll
    for (int i = 0; i < 4; ++i)
      af[i] = *(const bf16v8*)&lA[cur][(wr * 64 + i * 16 + l16) * 32 + g * 8];
#pragma unroll
    for (int j = 0; j < 3; ++j)
      bfv[j] = *(const bf16v8*)&lB[cur][(wc * 48 + j * 16 + l16) * 32 + g * 8];
#pragma unroll
    for (int i = 0; i < 4; ++i)
#pragma unroll
      for (int j = 0; j < 3; ++j)
        acc[i][j] = mfma16(af[i], bfv[j], acc[i][j]);
    __syncthreads();
  }
#undef QSTAGE

  const int row0 = m0 + wr * 64, col0 = n0 + wc * 48;
  if (n0 < 1536) {  // Q|K part -> QKb[row][col]
#pragma unroll
    for (int j = 0; j < 3; ++j) {
      const int col = col0 + j * 16 + l16;
      const float bcol = bias[col];
#pragma unroll
      for (int i = 0; i < 4; ++i)
#pragma unroll
        for (int r = 0; r < 4; ++r) {
          const int row = row0 + i * 16 + g * 4 + r;
          QKb[(size_t)row * 1536 + col] = f2b(acc[i][j][r] + bcol);
        }
    }
  } else {  // V part -> transposed store into Vtb[col-1536][row]
#pragma unroll
    for (int j = 0; j < 3; ++j) {
      const int col = col0 + j * 16 + l16;
      const float bcol = bias[col];
      const size_t vrow = (size_t)(col - 1536) * 8192;
#pragma unroll
      for (int i = 0; i < 4; ++i) {
        u16x4 pw;
#pragma unroll
        for (int r = 0; r < 4; ++r) pw[r] = f2b(acc[i][j][r] + bcol);
        *(u16x4*)&Vtb[vrow + row0 + i * 16 + g * 4] = pw;
      }
    }
  }
}

// ------------------------------------------------------------------ GEMM ----
// O-projection 128x96 (byte-identical to R17's passing version).
__global__ __launch_bounds__(256, 2) void gemm_o(
    const u16* __restrict__ A, const u16* __restrict__ Bt,
    float* __restrict__ C, const float* __restrict__ bias) {
  __shared__ u16 lA[2][128 * 32];
  __shared__ u16 lB[2][96 * 32];

  const int tid = threadIdx.x;
  const int lane = tid & 63, wid = tid >> 6;
  const int g = lane >> 4, l16 = lane & 15;
  const int rowb = wid * 32;
  const int m0 = blockIdx.x * 128, n0 = blockIdx.y * 96;

  const int srow = tid >> 2;
  const int scol = (tid & 3) * 16;

  f32x4 acc[2][6];
#pragma unroll
  for (int i = 0; i < 2; ++i)
#pragma unroll
    for (int j = 0; j < 6; ++j) acc[i][j] = (f32x4)0.f;

  const char* Ab = (const char*)(A + (size_t)m0 * 768);
  const char* Bb = (const char*)(Bt + (size_t)n0 * 768);
  char* lAb = (char*)&lA[0][0];
  char* lBb = (char*)&lB[0][0];

#define OSTAGE(buf, kt)                                                         \
  do {                                                                          \
    int kb = (kt) * 64;                                                         \
    gl_lds16(Ab + (size_t)srow * 1536 + kb + scol,                              \
             lAb + (buf) * 8192 + wid * 1024);                                  \
    gl_lds16(Ab + (size_t)(64 + srow) * 1536 + kb + scol,                       \
             lAb + (buf) * 8192 + 4096 + wid * 1024);                           \
    gl_lds16(Bb + (size_t)srow * 1536 + kb + scol,                              \
             lBb + (buf) * 6144 + wid * 1024);                                  \
    if (srow < 32)                                                              \
      gl_lds16(Bb + (size_t)(64 + srow) * 1536 + kb + scol,                     \
               lBb + (buf) * 6144 + 4096 + wid * 1024);                         \
  } while (0)

  OSTAGE(0, 0);
  __syncthreads();

  for (int kt = 0; kt < 24; ++kt) {
    const int cur = kt & 1;
    if (kt + 1 < 24) OSTAGE(cur ^ 1, kt + 1);
    bf16v8 af[2], bfv[6];
#pragma unroll
    for (int i = 0; i < 2; ++i)
      af[i] = *(const bf16v8*)&lA[cur][(rowb + i * 16 + l16) * 32 + g * 8];
#pragma unroll
    for (int j = 0; j < 6; ++j)
      bfv[j] = *(const bf16v8*)&lB[cur][(j * 16 + l16) * 32 + g * 8];
#pragma unroll
    for (int i = 0; i < 2; ++i)
#pragma unroll
      for (int j = 0; j < 6; ++j)
        acc[i][j] = mfma16(af[i], bfv[j], acc[i][j]);
    __syncthreads();
  }
#undef OSTAGE

  const int row0 = m0 + rowb;
#pragma unroll
  for (int j = 0; j < 6; ++j) {
    const int col = n0 + j * 16 + l16;
    const float bcol = bias[col];
#pragma unroll
    for (int i = 0; i < 2; ++i)
#pragma unroll
      for (int r = 0; r < 4; ++r) {
        const int row = row0 + i * 16 + g * 4 + r;
        C[(size_t)row * 768 + col] = acc[i][j][r] + bcol;
      }
  }
}

// ----------------------------------------------------------- flash attn ----
// R12's flash7, byte-identical (passed R10 + R12; sound fencing: each wave's
// counted vmcnt BEFORE the shared barrier).  flash9's post-barrier vmcnt was
// unsound (own-queue only) — reverted.
__global__ __launch_bounds__(256, 3) void flash7_kernel(
    const u16* __restrict__ QK, const u16* __restrict__ Vt,
    u16* __restrict__ Z) {
  __shared__ u16 lK[2][64 * 64];
  __shared__ u16 lV[2][64 * 64];
  __shared__ u16 lP[64 * 72];

  const int tid = threadIdx.x;
  const int lane = tid & 63, wid = tid >> 6;
  const int g = lane >> 4, l16 = lane & 15;

  const int id = blockIdx.x;
  const int xs = id & 7;
  const int rest = id >> 3;       // 0..95
  const int p = rest & 7;         // pair selector 0..7
  const int j = rest >> 3;        // 0..11
  const int head = xs + 8 * j;    // head%8 == xs (XCD grouping)
  const int b = head / 12, n = head % 12;

  const int nchA = 16 - p;        // phase A: half-block 15-p
  const int total = 17;           // + phase B: half-block p (p+1 chunks)

  const u16* Qh = QK + (size_t)b * 1024 * 1536 + n * 64;
  const u16* Kh = Qh + 768;
  const u16* Vh = Vt + (size_t)n * 64 * 8192 + b * 1024;
  u16* Zh = Z + (size_t)b * 1024 * 768 + n * 64;
  u16* myP = &lP[(wid * 16) * 72];

  const int srow8 = lane >> 3;
  const int sslot = lane & 7;
  const int scol = ((sslot ^ srow8) << 4);

#define FSTAGE(buf, c)                                                        \
  do {                                                                        \
    const int kv0_ = (c) << 6;                                                \
    const char* kb_ = (const char*)Kh + (size_t)(kv0_ + (wid << 4)) * 3072;   \
    const char* vb_ = (const char*)Vh + (size_t)(wid << 4) * 16384 +          \
                      (size_t)kv0_ * 2;                                       \
    gl_lds16(kb_ + (size_t)srow8 * 3072 + scol,                               \
             (char*)&lK[buf][0] + (wid << 11));                               \
    gl_lds16(kb_ + (size_t)(8 + srow8) * 3072 + scol,                         \
             (char*)&lK[buf][0] + (wid << 11) + 1024);                        \
    gl_lds16(vb_ + (size_t)srow8 * 16384 + scol,                              \
             (char*)&lV[buf][0] + (wid << 11));                               \
    gl_lds16(vb_ + (size_t)(8 + srow8) * 16384 + scol,                        \
             (char*)&lV[buf][0] + (wid << 11) + 1024);                        \
  } while (0)

#define SWZ(row, slot) (((row) << 6) + ((((slot) ^ ((row) & 7))) << 3))

  const int qwA = (15 - p) * 64 + wid * 16;
  const int qwB = p * 64 + wid * 16;
  bf16v8 qfA[2], qfB[2];
#pragma unroll
  for (int kk = 0; kk < 2; ++kk) {
    qfA[kk] = *(const bf16v8*)(Qh + (size_t)(qwA + l16) * 1536 + kk * 32 + g * 8);
    qfB[kk] = *(const bf16v8*)(Qh + (size_t)(qwB + l16) * 1536 + kk * 32 + g * 8);
  }

  f32x4 po[4];
#pragma unroll
  for (int ht = 0; ht < 4; ++ht) po[ht] = (f32x4)0.f;
  float m = -3e38f, l = 0.f;

  FSTAGE(0, 0);

  for (int s = 0; s < total; ++s) {
    const int cur = s & 1;
    const bool phB = s >= nchA;
    const int c = phB ? s - nchA : s;
    const int kv0 = c << 6;
    const int qw = phB ? qwB : qwA;

    if (s + 1 < total) {
      const int s1 = s + 1;
      const int c1 = (s1 >= nchA) ? s1 - nchA : s1;
      FSTAGE(cur ^ 1, c1);
      asm volatile("s_waitcnt vmcnt(4)" ::: "memory");
    } else {
      asm volatile("s_waitcnt vmcnt(0)" ::: "memory");
    }
    __builtin_amdgcn_s_barrier();
    __builtin_amdgcn_sched_barrier(0);

    const bf16v8 q0 = phB ? qfB[0] : qfA[0];
    const bf16v8 q1 = phB ? qfB[1] : qfA[1];

    bf16v8 kf[4][2];
#pragma unroll
    for (int kvt = 0; kvt < 4; ++kvt)
#pragma unroll
      for (int kk = 0; kk < 2; ++kk)
        kf[kvt][kk] =
            *(const bf16v8*)&lK[cur][SWZ(kvt * 16 + l16, kk * 4 + g)];
    f32x4 s_[4];
#pragma unroll
    for (int kvt = 0; kvt < 4; ++kvt) {
      f32x4 a = (f32x4)0.f;
      a = mfma16(kf[kvt][0], q0, a);
      a = mfma16(kf[kvt][1], q1, a);
      s_[kvt] = a;
    }
    bf16v8 vf[4][2];
#pragma unroll
    for (int ht = 0; ht < 4; ++ht)
#pragma unroll
      for (int kk = 0; kk < 2; ++kk)
        vf[ht][kk] =
            *(const bf16v8*)&lV[cur][SWZ(ht * 16 + l16, kk * 4 + g)];

    if (kv0 + 63 > qw) {
      const int qq = qw + l16;
#pragma unroll
      for (int kvt = 0; kvt < 4; ++kvt) {
        const int kv = kv0 + kvt * 16 + g * 4;
#pragma unroll
        for (int r = 0; r < 4; ++r)
          if (kv + r > qq) s_[kvt][r] = -3e38f;
      }
    }
    {
      float cm = s_[0][0];
#pragma unroll
      for (int kvt = 0; kvt < 4; ++kvt)
#pragma unroll
        for (int r = 0; r < 4; ++r) cm = fmaxf(cm, s_[kvt][r]);
      cm = fmaxf(cm, __shfl_xor(cm, 16));
      cm = fmaxf(cm, __shfl_xor(cm, 32));
      const bool defer = __all(cm - m <= 8.0f);
      float scl = 1.0f;
      if (!defer) {
        const float mn = fmaxf(m, cm);
        scl = exp2f(m - mn);
        m = mn;
#pragma unroll
        for (int r = 0; r < 4; ++r) {
          const float sr = __shfl(scl, g * 4 + r);
#pragma unroll
          for (int ht = 0; ht < 4; ++ht) po[ht][r] *= sr;
        }
      }
      float rs = 0.f;
#pragma unroll
      for (int kvt = 0; kvt < 4; ++kvt) {
        u16x4 pw;
#pragma unroll
        for (int r = 0; r < 4; ++r) {
          const float pv = exp2f(s_[kvt][r] - m);
          rs += pv;
          pw[r] = f2b(pv);
        }
        *(u16x4*)&myP[l16 * 72 + kvt * 16 + g * 4] = pw;
      }
      rs += __shfl_xor(rs, 16);
      rs += __shfl_xor(rs, 32);
      l = l * scl + rs;
    }
    bf16v8 pa[2];
#pragma unroll
    for (int kk = 0; kk < 2; ++kk)
      pa[kk] = *(const bf16v8*)&myP[l16 * 72 + kk * 32 + g * 8];
#pragma unroll
    for (int ht = 0; ht < 4; ++ht) {
      po[ht] = mfma16(pa[0], vf[ht][0], po[ht]);
      po[ht] = mfma16(pa[1], vf[ht][1], po[ht]);
    }

    __builtin_amdgcn_s_barrier();

    if (s == nchA - 1 || s == total - 1) {
#pragma unroll
      for (int r = 0; r < 4; ++r) {
        const float lr = __shfl(l, g * 4 + r);
        const float inv = 1.f / lr;
        const int qq = qw + g * 4 + r;
#pragma unroll
        for (int ht = 0; ht < 4; ++ht)
          Zh[(size_t)qq * 768 + ht * 16 + l16] = f2b(po[ht][r] * inv);
      }
      m = -3e38f;
      l = 0.f;
#pragma unroll
      for (int ht = 0; ht < 4; ++ht) po[ht] = (f32x4)0.f;
    }
  }
#undef FSTAGE
#undef SWZ
}

// ---------------------------------------------------------------- launch ----
extern "C" void kernel_launch(void* const* d_in, const int* in_sizes, int n_in,
                              void* d_out, int out_size, void* d_ws,
                              size_t ws_size, hipStream_t stream) {
  const float* x  = (const float*)d_in[0];
  const float* wq = (const float*)d_in[1];
  const float* wk = (const float*)d_in[2];
  const float* wv = (const float*)d_in[3];
  const float* wo = (const float*)d_in[4];
  const float* bq = (const float*)d_in[5];
  const float* bk = (const float*)d_in[6];
  const float* bv = (const float*)d_in[7];
  const float* bo = (const float*)d_in[8];
  float* out = (float*)d_out;

  const float sq = 0.18033688011112042f;  // log2(e) / sqrt(64)

  char* ws = (char*)d_ws;
  u16* Xb    = (u16*)ws; ws += 12582912;  // [8192][768] bf16
  u16* BtQKV = (u16*)ws; ws += 3538944;   // [2304][768] bf16: WqT*sq|WkT|WvT
  u16* WoT   = (u16*)ws; ws += 1179648;   // [768][768]
  float* bc  = (float*)ws; ws += 9216;    // [2304] fp32: bq*sq | bk | bv
  u16* QKb   = (u16*)ws; ws += 25165824;  // [8192][1536] (Q | K)
  u16* Vtb   = (u16*)ws; ws += 12582912;  // [768][8192]  (V transposed)
  u16* Zb    = (u16*)ws; ws += 12582912;  // [8192][768]

  pack_x_kernel<<<3081, 256, 0, stream>>>(x, Xb, 786432, bq, bk, bv, bc, sq);
  pack_w_all<<<dim3(12, 1, 48), 256, 0, stream>>>(wq, wk, wv, wo, BtQKV, WoT,
                                                  sq);

  // fused Q|K|V projection: 512 threads, 8 waves, 768 blocks (3/CU, 6 w/SIMD)
  gemm_qkv<<<dim3(64, 12), 512, 0, stream>>>(Xb, BtQKV, QKb, Vtb, bc);

  flash7_kernel<<<dim3(768), 256, 0, stream>>>(QKb, Vtb, Zb);

  gemm_o<<<dim3(64, 8), 256, 0, stream>>>(Zb, WoT, out, bo);
}

// Round 20
// 105.331 us; speedup vs baseline: 1.1030x; 1.1030x over previous
//
#include <hip/hip_runtime.h>
#include <stdint.h>

typedef __attribute__((ext_vector_type(4))) float f32x4;
typedef __attribute__((ext_vector_type(8))) __bf16 bf16v8;
typedef __attribute__((ext_vector_type(8))) unsigned short u16x8;
typedef __attribute__((ext_vector_type(4))) unsigned short u16x4;
typedef unsigned short u16;

#define AS1 __attribute__((address_space(1)))
#define AS3 __attribute__((address_space(3)))

__device__ __forceinline__ u16 f2b(float f) {
  union { __bf16 h; u16 u; } c; c.h = (__bf16)f; return c.u;
}

__device__ __forceinline__ f32x4 mfma16(bf16v8 a, bf16v8 b, f32x4 c) {
  return __builtin_amdgcn_mfma_f32_16x16x32_bf16(a, b, c, 0, 0, 0);
}

__device__ __forceinline__ void gl_lds16(const void* g, void* l) {
  __builtin_amdgcn_global_load_lds((AS1 void*)g, (AS3 void*)l, 16, 0, 0);
}

// -------------------------------------------- combined pack (one launch) ----
// blocks 0..3080: x fp32->bf16 (+ bias concat tail)
// blocks 3081..3656: weight 64x64 transpose tiles (which = z/12)
__global__ __launch_bounds__(256) void pack_all_kernel(
    const float* __restrict__ x, u16* __restrict__ xb, int n8,
    const float* __restrict__ bq, const float* __restrict__ bk,
    const float* __restrict__ bv, float* __restrict__ bc,
    const float* __restrict__ wq, const float* __restrict__ wk,
    const float* __restrict__ wv, const float* __restrict__ wo,
    u16* __restrict__ btqkv, u16* __restrict__ wot, float sq) {
  __shared__ float t[64][65];
  if (blockIdx.x < 3081) {
    int i = blockIdx.x * 256 + threadIdx.x;
    if (i < n8) {
      const f32x4* p = (const f32x4*)(x + (size_t)i * 8);
      f32x4 a = p[0], b = p[1];
      u16x8 o;
      o[0] = f2b(a[0]); o[1] = f2b(a[1]); o[2] = f2b(a[2]); o[3] = f2b(a[3]);
      o[4] = f2b(b[0]); o[5] = f2b(b[1]); o[6] = f2b(b[2]); o[7] = f2b(b[3]);
      *(u16x8*)(xb + (size_t)i * 8) = o;
    } else {
      int j = i - n8;
      if (j < 768) bc[j] = bq[j] * sq;
      else if (j < 1536) bc[j] = bk[j - 768];
      else if (j < 2304) bc[j] = bv[j - 1536];
    }
    return;
  }
  const int idx = blockIdx.x - 3081;       // 0..575
  const int xt = idx % 12;                 // tile index
  const int z = idx / 12;                  // 0..47
  const int which = z / 12, n = z % 12;
  const int c = threadIdx.x & 63, w = threadIdx.x >> 6;

  const float* in; u16* out; int in_rs; float scale;
  int a0, b0;
  if (which == 0)      { in = wq; out = btqkv;           in_rs = 64;  scale = sq;  }
  else if (which == 1) { in = wk; out = btqkv + 589824;  in_rs = 64;  scale = 1.f; }
  else if (which == 2) { in = wv; out = btqkv + 1179648; in_rs = 64;  scale = 1.f; }
  else                 { in = wo; out = wot;             in_rs = 768; scale = 1.f; }
  if (which < 3) { a0 = xt * 64; b0 = 0; }
  else           { a0 = 0; b0 = xt * 64; }

  const float* ip = in + (size_t)n * 49152;
#pragma unroll
  for (int i = 0; i < 16; ++i) {
    int r = i * 4 + w;
    t[r][c] = ip[(size_t)(a0 + r) * in_rs + (b0 + c)];
  }
  __syncthreads();
  u16* op = out + (size_t)n * ((which < 3) ? 49152 : 64);
#pragma unroll
  for (int i = 0; i < 16; ++i) {
    int r = i * 4 + w;
    op[(size_t)(b0 + r) * 768 + (a0 + c)] = f2b(t[c][r] * scale);
  }
}

// ------------------------------------------------- fused QKV projection ----
// R12's passing version (256 threads, 3 blocks/CU, one __syncthreads/K-step;
// measured 43.4 us = 668 TF, the 2-phase structure floor for this shape).
__global__ __launch_bounds__(256, 3) void gemm_qkv(
    const u16* __restrict__ A, const u16* __restrict__ Bt,
    u16* __restrict__ QKb, u16* __restrict__ Vtb,
    const float* __restrict__ bias) {
  __shared__ u16 lA[2][128 * 32];
  __shared__ u16 lB[2][192 * 32];

  const int tid = threadIdx.x;
  const int lane = tid & 63, wid = tid >> 6;
  const int g = lane >> 4, l16 = lane & 15;
  const int wr = wid >> 1, wc = wid & 1;
  const int m0 = blockIdx.x * 128, n0 = blockIdx.y * 192;

  const int srow = tid >> 2;
  const int scol = (tid & 3) * 16;

  f32x4 acc[4][6];
#pragma unroll
  for (int i = 0; i < 4; ++i)
#pragma unroll
    for (int j = 0; j < 6; ++j) acc[i][j] = (f32x4)0.f;

  const char* Ab = (const char*)(A + (size_t)m0 * 768);
  const char* Bb = (const char*)(Bt + (size_t)n0 * 768);
  char* lAb = (char*)&lA[0][0];
  char* lBb = (char*)&lB[0][0];

#define QSTAGE(buf, kt)                                                         \
  do {                                                                          \
    int kb = (kt) * 64;                                                         \
    gl_lds16(Ab + (size_t)srow * 1536 + kb + scol,                              \
             lAb + (buf) * 8192 + wid * 1024);                                  \
    gl_lds16(Ab + (size_t)(64 + srow) * 1536 + kb + scol,                       \
             lAb + (buf) * 8192 + 4096 + wid * 1024);                           \
    gl_lds16(Bb + (size_t)srow * 1536 + kb + scol,                              \
             lBb + (buf) * 12288 + wid * 1024);                                 \
    gl_lds16(Bb + (size_t)(64 + srow) * 1536 + kb + scol,                       \
             lBb + (buf) * 12288 + 4096 + wid * 1024);                          \
    gl_lds16(Bb + (size_t)(128 + srow) * 1536 + kb + scol,                      \
             lBb + (buf) * 12288 + 8192 + wid * 1024);                          \
  } while (0)

  QSTAGE(0, 0);
  __syncthreads();

  for (int kt = 0; kt < 24; ++kt) {
    const int cur = kt & 1;
    if (kt + 1 < 24) QSTAGE(cur ^ 1, kt + 1);
    bf16v8 af[4], bfv[6];
#pragma unroll
    for (int i = 0; i < 4; ++i)
      af[i] = *(const bf16v8*)&lA[cur][(wr * 64 + i * 16 + l16) * 32 + g * 8];
#pragma unroll
    for (int j = 0; j < 6; ++j)
      bfv[j] = *(const bf16v8*)&lB[cur][(wc * 96 + j * 16 + l16) * 32 + g * 8];
#pragma unroll
    for (int i = 0; i < 4; ++i)
#pragma unroll
      for (int j = 0; j < 6; ++j)
        acc[i][j] = mfma16(af[i], bfv[j], acc[i][j]);
    __syncthreads();
  }
#undef QSTAGE

  const int row0 = m0 + wr * 64, col0 = n0 + wc * 96;
  if (n0 < 1536) {  // Q|K part -> QKb[row][col]
#pragma unroll
    for (int j = 0; j < 6; ++j) {
      const int col = col0 + j * 16 + l16;
      const float bcol = bias[col];
#pragma unroll
      for (int i = 0; i < 4; ++i)
#pragma unroll
        for (int r = 0; r < 4; ++r) {
          const int row = row0 + i * 16 + g * 4 + r;
          QKb[(size_t)row * 1536 + col] = f2b(acc[i][j][r] + bcol);
        }
    }
  } else {  // V part -> transposed store into Vtb[col-1536][row]
#pragma unroll
    for (int j = 0; j < 6; ++j) {
      const int col = col0 + j * 16 + l16;
      const float bcol = bias[col];
      const size_t vrow = (size_t)(col - 1536) * 8192;
#pragma unroll
      for (int i = 0; i < 4; ++i) {
        u16x4 pw;
#pragma unroll
        for (int r = 0; r < 4; ++r) pw[r] = f2b(acc[i][j][r] + bcol);
        *(u16x4*)&Vtb[vrow + row0 + i * 16 + g * 4] = pw;
      }
    }
  }
}

// ------------------------------------------------------------------ GEMM ----
// O-projection 128x96 (R17's passing version).
__global__ __launch_bounds__(256, 2) void gemm_o(
    const u16* __restrict__ A, const u16* __restrict__ Bt,
    float* __restrict__ C, const float* __restrict__ bias) {
  __shared__ u16 lA[2][128 * 32];
  __shared__ u16 lB[2][96 * 32];

  const int tid = threadIdx.x;
  const int lane = tid & 63, wid = tid >> 6;
  const int g = lane >> 4, l16 = lane & 15;
  const int rowb = wid * 32;
  const int m0 = blockIdx.x * 128, n0 = blockIdx.y * 96;

  const int srow = tid >> 2;
  const int scol = (tid & 3) * 16;

  f32x4 acc[2][6];
#pragma unroll
  for (int i = 0; i < 2; ++i)
#pragma unroll
    for (int j = 0; j < 6; ++j) acc[i][j] = (f32x4)0.f;

  const char* Ab = (const char*)(A + (size_t)m0 * 768);
  const char* Bb = (const char*)(Bt + (size_t)n0 * 768);
  char* lAb = (char*)&lA[0][0];
  char* lBb = (char*)&lB[0][0];

#define OSTAGE(buf, kt)                                                         \
  do {                                                                          \
    int kb = (kt) * 64;                                                         \
    gl_lds16(Ab + (size_t)srow * 1536 + kb + scol,                              \
             lAb + (buf) * 8192 + wid * 1024);                                  \
    gl_lds16(Ab + (size_t)(64 + srow) * 1536 + kb + scol,                       \
             lAb + (buf) * 8192 + 4096 + wid * 1024);                           \
    gl_lds16(Bb + (size_t)srow * 1536 + kb + scol,                              \
             lBb + (buf) * 6144 + wid * 1024);                                  \
    if (srow < 32)                                                              \
      gl_lds16(Bb + (size_t)(64 + srow) * 1536 + kb + scol,                     \
               lBb + (buf) * 6144 + 4096 + wid * 1024);                         \
  } while (0)

  OSTAGE(0, 0);
  __syncthreads();

  for (int kt = 0; kt < 24; ++kt) {
    const int cur = kt & 1;
    if (kt + 1 < 24) OSTAGE(cur ^ 1, kt + 1);
    bf16v8 af[2], bfv[6];
#pragma unroll
    for (int i = 0; i < 2; ++i)
      af[i] = *(const bf16v8*)&lA[cur][(rowb + i * 16 + l16) * 32 + g * 8];
#pragma unroll
    for (int j = 0; j < 6; ++j)
      bfv[j] = *(const bf16v8*)&lB[cur][(j * 16 + l16) * 32 + g * 8];
#pragma unroll
    for (int i = 0; i < 2; ++i)
#pragma unroll
      for (int j = 0; j < 6; ++j)
        acc[i][j] = mfma16(af[i], bfv[j], acc[i][j]);
    __syncthreads();
  }
#undef OSTAGE

  const int row0 = m0 + rowb;
#pragma unroll
  for (int j = 0; j < 6; ++j) {
    const int col = n0 + j * 16 + l16;
    const float bcol = bias[col];
#pragma unroll
    for (int i = 0; i < 2; ++i)
#pragma unroll
      for (int r = 0; r < 4; ++r) {
        const int row = row0 + i * 16 + g * 4 + r;
        C[(size_t)row * 768 + col] = acc[i][j][r] + bcol;
      }
  }
}

// ----------------------------------------------------------- flash attn ----
// R12's flash7, byte-identical (passed R10/R12/R17/R18).
__global__ __launch_bounds__(256, 3) void flash7_kernel(
    const u16* __restrict__ QK, const u16* __restrict__ Vt,
    u16* __restrict__ Z) {
  __shared__ u16 lK[2][64 * 64];
  __shared__ u16 lV[2][64 * 64];
  __shared__ u16 lP[64 * 72];

  const int tid = threadIdx.x;
  const int lane = tid & 63, wid = tid >> 6;
  const int g = lane >> 4, l16 = lane & 15;

  const int id = blockIdx.x;
  const int xs = id & 7;
  const int rest = id >> 3;       // 0..95
  const int p = rest & 7;         // pair selector 0..7
  const int j = rest >> 3;        // 0..11
  const int head = xs + 8 * j;    // head%8 == xs (XCD grouping)
  const int b = head / 12, n = head % 12;

  const int nchA = 16 - p;        // phase A: half-block 15-p
  const int total = 17;           // + phase B: half-block p (p+1 chunks)

  const u16* Qh = QK + (size_t)b * 1024 * 1536 + n * 64;
  const u16* Kh = Qh + 768;
  const u16* Vh = Vt + (size_t)n * 64 * 8192 + b * 1024;
  u16* Zh = Z + (size_t)b * 1024 * 768 + n * 64;
  u16* myP = &lP[(wid * 16) * 72];

  const int srow8 = lane >> 3;
  const int sslot = lane & 7;
  const int scol = ((sslot ^ srow8) << 4);

#define FSTAGE(buf, c)                                                        \
  do {                                                                        \
    const int kv0_ = (c) << 6;                                                \
    const char* kb_ = (const char*)Kh + (size_t)(kv0_ + (wid << 4)) * 3072;   \
    const char* vb_ = (const char*)Vh + (size_t)(wid << 4) * 16384 +          \
                      (size_t)kv0_ * 2;                                       \
    gl_lds16(kb_ + (size_t)srow8 * 3072 + scol,                               \
             (char*)&lK[buf][0] + (wid << 11));                               \
    gl_lds16(kb_ + (size_t)(8 + srow8) * 3072 + scol,                         \
             (char*)&lK[buf][0] + (wid << 11) + 1024);                        \
    gl_lds16(vb_ + (size_t)srow8 * 16384 + scol,                              \
             (char*)&lV[buf][0] + (wid << 11));                               \
    gl_lds16(vb_ + (size_t)(8 + srow8) * 16384 + scol,                        \
             (char*)&lV[buf][0] + (wid << 11) + 1024);                        \
  } while (0)

#define SWZ(row, slot) (((row) << 6) + ((((slot) ^ ((row) & 7))) << 3))

  const int qwA = (15 - p) * 64 + wid * 16;
  const int qwB = p * 64 + wid * 16;
  bf16v8 qfA[2], qfB[2];
#pragma unroll
  for (int kk = 0; kk < 2; ++kk) {
    qfA[kk] = *(const bf16v8*)(Qh + (size_t)(qwA + l16) * 1536 + kk * 32 + g * 8);
    qfB[kk] = *(const bf16v8*)(Qh + (size_t)(qwB + l16) * 1536 + kk * 32 + g * 8);
  }

  f32x4 po[4];
#pragma unroll
  for (int ht = 0; ht < 4; ++ht) po[ht] = (f32x4)0.f;
  float m = -3e38f, l = 0.f;

  FSTAGE(0, 0);

  for (int s = 0; s < total; ++s) {
    const int cur = s & 1;
    const bool phB = s >= nchA;
    const int c = phB ? s - nchA : s;
    const int kv0 = c << 6;
    const int qw = phB ? qwB : qwA;

    if (s + 1 < total) {
      const int s1 = s + 1;
      const int c1 = (s1 >= nchA) ? s1 - nchA : s1;
      FSTAGE(cur ^ 1, c1);
      asm volatile("s_waitcnt vmcnt(4)" ::: "memory");
    } else {
      asm volatile("s_waitcnt vmcnt(0)" ::: "memory");
    }
    __builtin_amdgcn_s_barrier();
    __builtin_amdgcn_sched_barrier(0);

    const bf16v8 q0 = phB ? qfB[0] : qfA[0];
    const bf16v8 q1 = phB ? qfB[1] : qfA[1];

    bf16v8 kf[4][2];
#pragma unroll
    for (int kvt = 0; kvt < 4; ++kvt)
#pragma unroll
      for (int kk = 0; kk < 2; ++kk)
        kf[kvt][kk] =
            *(const bf16v8*)&lK[cur][SWZ(kvt * 16 + l16, kk * 4 + g)];
    f32x4 s_[4];
#pragma unroll
    for (int kvt = 0; kvt < 4; ++kvt) {
      f32x4 a = (f32x4)0.f;
      a = mfma16(kf[kvt][0], q0, a);
      a = mfma16(kf[kvt][1], q1, a);
      s_[kvt] = a;
    }
    bf16v8 vf[4][2];
#pragma unroll
    for (int ht = 0; ht < 4; ++ht)
#pragma unroll
      for (int kk = 0; kk < 2; ++kk)
        vf[ht][kk] =
            *(const bf16v8*)&lV[cur][SWZ(ht * 16 + l16, kk * 4 + g)];

    if (kv0 + 63 > qw) {
      const int qq = qw + l16;
#pragma unroll
      for (int kvt = 0; kvt < 4; ++kvt) {
        const int kv = kv0 + kvt * 16 + g * 4;
#pragma unroll
        for (int r = 0; r < 4; ++r)
          if (kv + r > qq) s_[kvt][r] = -3e38f;
      }
    }
    {
      float cm = s_[0][0];
#pragma unroll
      for (int kvt = 0; kvt < 4; ++kvt)
#pragma unroll
        for (int r = 0; r < 4; ++r) cm = fmaxf(cm, s_[kvt][r]);
      cm = fmaxf(cm, __shfl_xor(cm, 16));
      cm = fmaxf(cm, __shfl_xor(cm, 32));
      const bool defer = __all(cm - m <= 8.0f);
      float scl = 1.0f;
      if (!defer) {
        const float mn = fmaxf(m, cm);
        scl = exp2f(m - mn);
        m = mn;
#pragma unroll
        for (int r = 0; r < 4; ++r) {
          const float sr = __shfl(scl, g * 4 + r);
#pragma unroll
          for (int ht = 0; ht < 4; ++ht) po[ht][r] *= sr;
        }
      }
      float rs = 0.f;
#pragma unroll
      for (int kvt = 0; kvt < 4; ++kvt) {
        u16x4 pw;
#pragma unroll
        for (int r = 0; r < 4; ++r) {
          const float pv = exp2f(s_[kvt][r] - m);
          rs += pv;
          pw[r] = f2b(pv);
        }
        *(u16x4*)&myP[l16 * 72 + kvt * 16 + g * 4] = pw;
      }
      rs += __shfl_xor(rs, 16);
      rs += __shfl_xor(rs, 32);
      l = l * scl + rs;
    }
    bf16v8 pa[2];
#pragma unroll
    for (int kk = 0; kk < 2; ++kk)
      pa[kk] = *(const bf16v8*)&myP[l16 * 72 + kk * 32 + g * 8];
#pragma unroll
    for (int ht = 0; ht < 4; ++ht) {
      po[ht] = mfma16(pa[0], vf[ht][0], po[ht]);
      po[ht] = mfma16(pa[1], vf[ht][1], po[ht]);
    }

    __builtin_amdgcn_s_barrier();

    if (s == nchA - 1 || s == total - 1) {
#pragma unroll
      for (int r = 0; r < 4; ++r) {
        const float lr = __shfl(l, g * 4 + r);
        const float inv = 1.f / lr;
        const int qq = qw + g * 4 + r;
#pragma unroll
        for (int ht = 0; ht < 4; ++ht)
          Zh[(size_t)qq * 768 + ht * 16 + l16] = f2b(po[ht][r] * inv);
      }
      m = -3e38f;
      l = 0.f;
#pragma unroll
      for (int ht = 0; ht < 4; ++ht) po[ht] = (f32x4)0.f;
    }
  }
#undef FSTAGE
#undef SWZ
}

// ---------------------------------------------------------------- launch ----
extern "C" void kernel_launch(void* const* d_in, const int* in_sizes, int n_in,
                              void* d_out, int out_size, void* d_ws,
                              size_t ws_size, hipStream_t stream) {
  const float* x  = (const float*)d_in[0];
  const float* wq = (const float*)d_in[1];
  const float* wk = (const float*)d_in[2];
  const float* wv = (const float*)d_in[3];
  const float* wo = (const float*)d_in[4];
  const float* bq = (const float*)d_in[5];
  const float* bk = (const float*)d_in[6];
  const float* bv = (const float*)d_in[7];
  const float* bo = (const float*)d_in[8];
  float* out = (float*)d_out;

  const float sq = 0.18033688011112042f;  // log2(e) / sqrt(64)

  char* ws = (char*)d_ws;
  u16* Xb    = (u16*)ws; ws += 12582912;  // [8192][768] bf16
  u16* BtQKV = (u16*)ws; ws += 3538944;   // [2304][768] bf16: WqT*sq|WkT|WvT
  u16* WoT   = (u16*)ws; ws += 1179648;   // [768][768]
  float* bc  = (float*)ws; ws += 9216;    // [2304] fp32: bq*sq | bk | bv
  u16* QKb   = (u16*)ws; ws += 25165824;  // [8192][1536] (Q | K)
  u16* Vtb   = (u16*)ws; ws += 12582912;  // [768][8192]  (V transposed)
  u16* Zb    = (u16*)ws; ws += 12582912;  // [8192][768]

  // all packing in one launch (blocks 0..3080 = x, 3081..3656 = weights)
  pack_all_kernel<<<3657, 256, 0, stream>>>(x, Xb, 786432, bq, bk, bv, bc,
                                            wq, wk, wv, wo, BtQKV, WoT, sq);

  gemm_qkv<<<dim3(64, 12), 256, 0, stream>>>(Xb, BtQKV, QKb, Vtb, bc);

  flash7_kernel<<<dim3(768), 256, 0, stream>>>(QKb, Vtb, Zb);

  gemm_o<<<dim3(64, 8), 256, 0, stream>>>(Zb, WoT, out, bo);
}